// Round 1
// baseline (1262.875 us; speedup 1.0000x reference)
//
#include <hip/hip_runtime.h>
#include <cstdint>
#include <cstddef>

// ---------------------------------------------------------------------------
// EarthSpecificBlock (Pangu-style 3D window attention block) for MI355X.
// B=2, L=57600 (8x60x120), C=256, H=8, hd=32, WIN=(2,6,12) -> N=144,
// nW=40 window types, B_=20, HID=1024.
// All GEMMs in bf16 MFMA (16x16x32), LN/softmax/residuals in fp32.
// ---------------------------------------------------------------------------

typedef __attribute__((ext_vector_type(8))) short bf16x8;
typedef __attribute__((ext_vector_type(4))) float f32x4;
typedef unsigned short ushort_t;

#define MFMA16(a, b, c) __builtin_amdgcn_mfma_f32_16x16x32_bf16(a, b, c, 0, 0, 0)

__device__ __forceinline__ unsigned short f2bf(float f) {
  union { float f; unsigned u; } c; c.f = f;
  unsigned r = c.u + 0x7FFFu + ((c.u >> 16) & 1u);   // RNE
  return (unsigned short)(r >> 16);
}

__device__ __forceinline__ void gload16(const void* g, void* l) {
  // LDS dest is wave-uniform base; HW adds lane*16 (m104/m108).
  __builtin_amdgcn_global_load_lds(
      (const __attribute__((address_space(1))) unsigned int*)g,
      (__attribute__((address_space(3))) unsigned int*)(uintptr_t)l,
      16, 0, 0);
}

// ---------------------------------------------------------------------------
// f32 -> bf16 weight convert
// ---------------------------------------------------------------------------
__global__ void cvt_kernel(const float* __restrict__ in, ushort_t* __restrict__ out, int n) {
  int i = blockIdx.x * 256 + threadIdx.x;
  if (i < n) out[i] = f2bf(in[i]);
}

// ---------------------------------------------------------------------------
// LayerNorm over C=256, one wave per token, fp32 in -> bf16 out
// ---------------------------------------------------------------------------
__global__ __launch_bounds__(256) void ln_kernel(
    const float* __restrict__ in, const float* __restrict__ g,
    const float* __restrict__ b, ushort_t* __restrict__ out) {
  const int wid = threadIdx.x >> 6, lane = threadIdx.x & 63;
  const size_t tok = (size_t)blockIdx.x * 4 + wid;
  const float4 v = *(const float4*)(in + tok * 256 + lane * 4);
  float s  = v.x + v.y + v.z + v.w;
  float sq = v.x * v.x + v.y * v.y + v.z * v.z + v.w * v.w;
#pragma unroll
  for (int off = 1; off < 64; off <<= 1) {
    s  += __shfl_xor(s, off);
    sq += __shfl_xor(sq, off);
  }
  const float mu = s * (1.0f / 256.0f);
  const float rs = rsqrtf(sq * (1.0f / 256.0f) - mu * mu + 1e-5f);
  const float4 gg = *(const float4*)(g + lane * 4);
  const float4 bb = *(const float4*)(b + lane * 4);
  ushort4 st;
  st.x = f2bf((v.x - mu) * rs * gg.x + bb.x);
  st.y = f2bf((v.y - mu) * rs * gg.y + bb.y);
  st.z = f2bf((v.z - mu) * rs * gg.z + bb.z);
  st.w = f2bf((v.w - mu) * rs * gg.w + bb.w);
  *(ushort4*)(out + tok * 256 + lane * 4) = st;
}

// ---------------------------------------------------------------------------
// Earth position bias gather: out[h][w][n][m] = tbl[posidx(n,m)][w][h]
// ---------------------------------------------------------------------------
__global__ void bias_gather(const float* __restrict__ tbl, float* __restrict__ out) {
  const int t = blockIdx.x * 256 + threadIdx.x;   // exact grid: 8*40*144*144
  const int m = t % 144;
  const int n = (t / 144) % 144;
  const int w = (t / 20736) % 40;
  const int h = t / 829440;
  const int zq = n / 72, hq = (n / 12) % 6, wq = n % 12;
  const int zk = m / 72, hk = (m / 12) % 6, wk = m % 12;
  const int idx = (zq + 2 * zk) * 828 + (hq + 6 * hk) * 23 + (wq - wk + 11);
  out[t] = tbl[idx * 320 + w * 8 + h];
}

// ---------------------------------------------------------------------------
// bf16 MFMA GEMM: C[M][N] = A[M][K] * Bw[N][K]^T, 128x128 tile, BK=64,
// 4 waves (each 64x64), global_load_lds + st-16x32-style XOR swizzle.
// EPI: 0 = qkv (bias + q-scale, bf16 out)
//      1 = proj (bias + residual fp32 out)
//      2 = fc1  (bias + exact gelu, bf16 out)
//      3 = fc2  (bias + residual fp32 out, in-place on res)
// ---------------------------------------------------------------------------
template <int EPI>
__global__ __launch_bounds__(256) void gemm_kernel(
    const ushort_t* __restrict__ A, const ushort_t* __restrict__ Bw,
    const float* __restrict__ bias, const float* __restrict__ res,
    void* __restrict__ outp, int M, int N, int K) {
  __shared__ unsigned char lds[32768];
  unsigned char* ldsA = lds;
  unsigned char* ldsB = lds + 16384;
  const int tid = threadIdx.x;
  const int lane = tid & 63, wid = tid >> 6;
  const int ntn = N >> 7;
  const int tileM = (int)(blockIdx.x / ntn) << 7;
  const int tileN = (int)(blockIdx.x % ntn) << 7;
  const unsigned baseoff = ((unsigned)wid << 10) | ((unsigned)lane << 4);

  f32x4 acc[4][4];
#pragma unroll
  for (int i = 0; i < 4; i++)
#pragma unroll
    for (int j = 0; j < 4; j++) acc[i][j] = (f32x4){0.f, 0.f, 0.f, 0.f};

  const int wm = (wid >> 1) << 6;
  const int wn = (wid & 1) << 6;

  for (int k0 = 0; k0 < K; k0 += 64) {
    // stage A,B tiles (each 128 rows x 128B); source pre-swizzled so LDS
    // layout is row*128 + (cb ^ ((row&7)<<4))
#pragma unroll
    for (int i = 0; i < 4; i++) {
      const unsigned o = baseoff + (unsigned)i * 4096u;
      const unsigned row = o >> 7, cb = o & 127u;
      const unsigned scb = cb ^ ((row & 7u) << 4);
      gload16(A + (size_t)(tileM + row) * K + k0 + (scb >> 1),
              ldsA + (i << 12) + (wid << 10));
      gload16(Bw + (size_t)(tileN + row) * K + k0 + (scb >> 1),
              ldsB + (i << 12) + (wid << 10));
    }
    asm volatile("s_waitcnt vmcnt(0)" ::: "memory");
    __syncthreads();
#pragma unroll
    for (int ks = 0; ks < 2; ks++) {
      bf16x8 af[4], bf[4];
#pragma unroll
      for (int mi = 0; mi < 4; mi++) {
        const int row = wm + mi * 16 + (lane & 15);
        const unsigned cb = ((unsigned)(ks * 64) + (((unsigned)lane >> 4) << 4)) ^ ((row & 7) << 4);
        af[mi] = *(const bf16x8*)(ldsA + row * 128 + cb);
      }
#pragma unroll
      for (int ni = 0; ni < 4; ni++) {
        const int row = wn + ni * 16 + (lane & 15);
        const unsigned cb = ((unsigned)(ks * 64) + (((unsigned)lane >> 4) << 4)) ^ ((row & 7) << 4);
        bf[ni] = *(const bf16x8*)(ldsB + row * 128 + cb);
      }
#pragma unroll
      for (int mi = 0; mi < 4; mi++)
#pragma unroll
        for (int ni = 0; ni < 4; ni++)
          acc[mi][ni] = MFMA16(af[mi], bf[ni], acc[mi][ni]);
    }
    __syncthreads();
  }

  // epilogue: D row=(lane>>4)*4+r, col=lane&15 (m89-verified)
  const int cr = ((lane >> 4) << 2);
  const int cc = lane & 15;
#pragma unroll
  for (int mi = 0; mi < 4; mi++) {
#pragma unroll
    for (int ni = 0; ni < 4; ni++) {
      const int colg = tileN + wn + ni * 16 + cc;
      const float bv = bias[colg];
#pragma unroll
      for (int r = 0; r < 4; r++) {
        const int rowg = tileM + wm + mi * 16 + cr + r;
        const size_t oidx = (size_t)rowg * N + colg;
        float v = acc[mi][ni][r] + bv;
        if (EPI == 0) {
          if (colg < 256) v *= 0.17677669529663687f;  // hd^-0.5, q only
          ((ushort_t*)outp)[oidx] = f2bf(v);
        } else if (EPI == 1) {
          ((float*)outp)[oidx] = v + res[oidx];
        } else if (EPI == 2) {
          const float ge = 0.5f * v * (1.0f + erff(v * 0.7071067811865475f));
          ((ushort_t*)outp)[oidx] = f2bf(ge);
        } else {
          ((float*)outp)[oidx] = v + res[oidx];
        }
      }
    }
  }
}

// ---------------------------------------------------------------------------
// Window attention: one block per (b_, w, h). N=144, hd=32.
// S = QK^T + bias (fp32 LDS), softmax, O = P V, scatter to natural order.
// ---------------------------------------------------------------------------
__device__ __forceinline__ int Lidx3(int n, int pi, int li, int ln) {
  const int wp = n / 72, rem = n - wp * 72;
  const int wl = rem / 12, ww = rem - wl * 12;
  return ((pi * 2 + wp) * 60 + li * 6 + wl) * 120 + ln * 12 + ww;
}

__global__ __launch_bounds__(256) void attn_kernel(
    const ushort_t* __restrict__ qkv,      // [B*L][768] bf16 (q pre-scaled)
    const float* __restrict__ biasArr,     // [8][40][144][144] fp32
    ushort_t* __restrict__ outp) {         // [B*L][256] bf16
  __shared__ ushort_t Qs[144 * 40];
  __shared__ ushort_t Ks[144 * 40];
  __shared__ ushort_t Vt[32 * 168];        // V^T, K-dim padded to 160 (zeros)
  __shared__ float    Sm[144 * 145];
  __shared__ ushort_t Pb[144 * 160];

  const int bi = blockIdx.x;
  const int h  = bi & 7;
  const int w  = (bi >> 3) % 40;
  const int b_ = bi / 320;
  const int b  = b_ / 10, ln = b_ % 10;
  const int pi = w / 10,  li = w % 10;
  const int tid = threadIdx.x, lane = tid & 63, wid = tid >> 6;

  // stage Q, K: [144][32] bf16, LDS stride 40 elems (80B)
  for (int idx = tid; idx < 144 * 4; idx += 256) {
    const int n = idx >> 2, seg = idx & 3;
    const size_t rb = ((size_t)b * 57600 + Lidx3(n, pi, li, ln)) * 768 + h * 32 + seg * 8;
    *(uint4*)(Qs + n * 40 + seg * 8) = *(const uint4*)(qkv + rb);
    *(uint4*)(Ks + n * 40 + seg * 8) = *(const uint4*)(qkv + rb + 256);
  }
  // stage V transposed: Vt[e][m], m padded 144..159 = 0
  for (int idx = tid; idx < 160 * 32; idx += 256) {
    const int n = idx >> 5, e = idx & 31;
    ushort_t val = 0;
    if (n < 144) {
      const size_t rb = ((size_t)b * 57600 + Lidx3(n, pi, li, ln)) * 768 + 512 + h * 32 + e;
      val = qkv[rb];
    }
    Vt[e * 168 + n] = val;
  }
  __syncthreads();

  // S = QK^T + bias ; 81 fragments of 16x16, round-robin over 4 waves
  const float* bslice = biasArr + (size_t)(h * 40 + w) * 20736;
  for (int f = wid; f < 81; f += 4) {
    const int fr = f / 9, fc = f % 9;
    const bf16x8 a  = *(const bf16x8*)(Qs + (fr * 16 + (lane & 15)) * 40 + ((lane >> 4) << 3));
    const bf16x8 bb = *(const bf16x8*)(Ks + (fc * 16 + (lane & 15)) * 40 + ((lane >> 4) << 3));
    f32x4 acc = (f32x4){0.f, 0.f, 0.f, 0.f};
    acc = MFMA16(a, bb, acc);
    const int m  = fc * 16 + (lane & 15);
    const int nb = fr * 16 + ((lane >> 4) << 2);
#pragma unroll
    for (int r = 0; r < 4; r++)
      Sm[(nb + r) * 145 + m] = acc[r] + bslice[(nb + r) * 144 + m];
  }
  __syncthreads();

  // row softmax (threads 0..143), write bf16 P with zero pad to 160 cols
  if (tid < 144) {
    float* row = Sm + tid * 145;
    float mx = -1e30f;
    for (int j = 0; j < 144; j++) mx = fmaxf(mx, row[j]);
    float sum = 0.f;
    for (int j = 0; j < 144; j++) { const float e = __expf(row[j] - mx); row[j] = e; sum += e; }
    const float inv = 1.0f / sum;
    ushort_t* prow = Pb + tid * 160;
    for (int j = 0; j < 144; j++) prow[j] = f2bf(row[j] * inv);
    for (int j = 144; j < 160; j++) prow[j] = 0;
  }
  __syncthreads();

  // O = P V : 9x2 fragments, K=160 (5 MFMA steps)
  for (int f = wid; f < 18; f += 4) {
    const int fr = f >> 1, fcv = f & 1;
    f32x4 acc = (f32x4){0.f, 0.f, 0.f, 0.f};
#pragma unroll
    for (int kb = 0; kb < 5; kb++) {
      const bf16x8 a  = *(const bf16x8*)(Pb + (fr * 16 + (lane & 15)) * 160 + kb * 32 + ((lane >> 4) << 3));
      const bf16x8 bb = *(const bf16x8*)(Vt + (fcv * 16 + (lane & 15)) * 168 + kb * 32 + ((lane >> 4) << 3));
      acc = MFMA16(a, bb, acc);
    }
    const int e  = fcv * 16 + (lane & 15);
    const int nb = fr * 16 + ((lane >> 4) << 2);
#pragma unroll
    for (int r = 0; r < 4; r++) {
      const int n = nb + r;
      const size_t ob = ((size_t)b * 57600 + Lidx3(n, pi, li, ln)) * 256 + h * 32 + e;
      outp[ob] = f2bf(acc[r]);
    }
  }
}

// ---------------------------------------------------------------------------
// launch
// ---------------------------------------------------------------------------
extern "C" void kernel_launch(void* const* d_in, const int* in_sizes, int n_in,
                              void* d_out, int out_size, void* d_ws, size_t ws_size,
                              hipStream_t stream) {
  const float* x      = (const float*)d_in[0];
  const float* n1g    = (const float*)d_in[1];
  const float* n1b    = (const float*)d_in[2];
  const float* qkv_w  = (const float*)d_in[3];
  const float* qkv_b  = (const float*)d_in[4];
  const float* btab   = (const float*)d_in[5];
  const float* proj_w = (const float*)d_in[6];
  const float* proj_b = (const float*)d_in[7];
  const float* n2g    = (const float*)d_in[8];
  const float* n2b    = (const float*)d_in[9];
  const float* fc1_w  = (const float*)d_in[10];
  const float* fc1_b  = (const float*)d_in[11];
  const float* fc2_w  = (const float*)d_in[12];
  const float* fc2_b  = (const float*)d_in[13];
  float* outp = (float*)d_out;

  char* ws = (char*)d_ws;
  // layout (peak ~296.5 MB):
  //  [0, 176.9M)   qkv bf16 [115200][768]     (later: ln2 out in first 59M)
  //  [176.9M, 235.9M) ln1 out bf16 (later: attn out bf16)
  //  [235.9M, 262.5M) bias fp32 [8][40][144][144]
  //  [59.0M, 294.9M)  fc1 out bf16 [115200][1024]  (after attention is done)
  //  [294.9M, 296.5M) bf16 weights
  ushort_t* qkvbuf = (ushort_t*)(ws);
  ushort_t* hbuf   = (ushort_t*)(ws + 176947200);
  float*    biasA  = (float*)(ws + 235929600);
  ushort_t* ln2buf = (ushort_t*)(ws);
  ushort_t* fc1buf = (ushort_t*)(ws + 58982400);
  ushort_t* wbuf   = (ushort_t*)(ws + 294912000);
  ushort_t* qkvW = wbuf;
  ushort_t* projW = wbuf + 196608;
  ushort_t* fc1W  = wbuf + 262144;
  ushort_t* fc2W  = wbuf + 524288;

  // weight converts
  cvt_kernel<<<768,  256, 0, stream>>>(qkv_w,  qkvW, 196608);
  cvt_kernel<<<256,  256, 0, stream>>>(proj_w, projW, 65536);
  cvt_kernel<<<1024, 256, 0, stream>>>(fc1_w,  fc1W, 262144);
  cvt_kernel<<<1024, 256, 0, stream>>>(fc2_w,  fc2W, 262144);

  // LN1 + bias gather
  ln_kernel<<<28800, 256, 0, stream>>>(x, n1g, n1b, hbuf);
  bias_gather<<<25920, 256, 0, stream>>>(btab, biasA);

  // QKV
  gemm_kernel<0><<<900 * 6, 256, 0, stream>>>(hbuf, qkvW, qkv_b, nullptr, qkvbuf, 115200, 768, 256);
  // attention (writes attn out into hbuf)
  attn_kernel<<<6400, 256, 0, stream>>>(qkvbuf, biasA, hbuf);
  // proj + residual(x) -> d_out (= x1)
  gemm_kernel<1><<<900 * 2, 256, 0, stream>>>(hbuf, projW, proj_b, x, outp, 115200, 256, 256);
  // LN2 on x1
  ln_kernel<<<28800, 256, 0, stream>>>(outp, n2g, n2b, ln2buf);
  // FC1 + gelu
  gemm_kernel<2><<<900 * 8, 256, 0, stream>>>(ln2buf, fc1W, fc1_b, nullptr, fc1buf, 115200, 1024, 256);
  // FC2 + residual(x1) -> d_out
  gemm_kernel<3><<<900 * 2, 256, 0, stream>>>(fc1buf, fc2W, fc2_b, outp, outp, 115200, 256, 1024);
}

// Round 2
// 936.228 us; speedup vs baseline: 1.3489x; 1.3489x over previous
//
#include <hip/hip_runtime.h>
#include <cstdint>
#include <cstddef>

// ---------------------------------------------------------------------------
// EarthSpecificBlock (Pangu-style 3D window attention block) for MI355X.
// B=2, L=57600 (8x60x120), C=256, H=8, hd=32, WIN=(2,6,12) -> N=144,
// nW=40 window types, B_=20, HID=1024.
// All GEMMs in bf16 MFMA (16x16x32), LN/softmax/residuals in fp32.
// ---------------------------------------------------------------------------

typedef __attribute__((ext_vector_type(8))) short bf16x8;
typedef __attribute__((ext_vector_type(4))) float f32x4;
typedef unsigned short ushort_t;

#define MFMA16(a, b, c) __builtin_amdgcn_mfma_f32_16x16x32_bf16(a, b, c, 0, 0, 0)

__device__ __forceinline__ unsigned short f2bf(float f) {
  union { float f; unsigned u; } c; c.f = f;
  unsigned r = c.u + 0x7FFFu + ((c.u >> 16) & 1u);   // RNE
  return (unsigned short)(r >> 16);
}

__device__ __forceinline__ void gload16(const void* g, void* l) {
  __builtin_amdgcn_global_load_lds(
      (const __attribute__((address_space(1))) unsigned int*)g,
      (__attribute__((address_space(3))) unsigned int*)(uintptr_t)l,
      16, 0, 0);
}

// ---------------------------------------------------------------------------
// f32 -> bf16 weight convert
// ---------------------------------------------------------------------------
__global__ void cvt_kernel(const float* __restrict__ in, ushort_t* __restrict__ out, int n) {
  int i = blockIdx.x * 256 + threadIdx.x;
  if (i < n) out[i] = f2bf(in[i]);
}

// ---------------------------------------------------------------------------
// bias table transpose: tblT[w*8+h][idx] = tbl[idx][w][h]   (3312 x 40 x 8)
// ---------------------------------------------------------------------------
__global__ void tbl_transpose(const float* __restrict__ tbl, float* __restrict__ out) {
  const int i = blockIdx.x * 256 + threadIdx.x;   // over 320*3312, coalesced writes
  if (i < 320 * 3312) {
    const int wh = i / 3312, idx = i % 3312;
    out[i] = tbl[idx * 320 + wh];
  }
}

// ---------------------------------------------------------------------------
// LayerNorm over C=256, one wave per token, fp32 in -> bf16 out
// ---------------------------------------------------------------------------
__global__ __launch_bounds__(256) void ln_kernel(
    const float* __restrict__ in, const float* __restrict__ g,
    const float* __restrict__ b, ushort_t* __restrict__ out) {
  const int wid = threadIdx.x >> 6, lane = threadIdx.x & 63;
  const size_t tok = (size_t)blockIdx.x * 4 + wid;
  const float4 v = *(const float4*)(in + tok * 256 + lane * 4);
  float s  = v.x + v.y + v.z + v.w;
  float sq = v.x * v.x + v.y * v.y + v.z * v.z + v.w * v.w;
#pragma unroll
  for (int off = 1; off < 64; off <<= 1) {
    s  += __shfl_xor(s, off);
    sq += __shfl_xor(sq, off);
  }
  const float mu = s * (1.0f / 256.0f);
  const float rs = rsqrtf(sq * (1.0f / 256.0f) - mu * mu + 1e-5f);
  const float4 gg = *(const float4*)(g + lane * 4);
  const float4 bb = *(const float4*)(b + lane * 4);
  ushort4 st;
  st.x = f2bf((v.x - mu) * rs * gg.x + bb.x);
  st.y = f2bf((v.y - mu) * rs * gg.y + bb.y);
  st.z = f2bf((v.z - mu) * rs * gg.z + bb.z);
  st.w = f2bf((v.w - mu) * rs * gg.w + bb.w);
  *(ushort4*)(out + tok * 256 + lane * 4) = st;
}

// ---------------------------------------------------------------------------
// bf16 MFMA GEMM: C[M][N] = A[M][K] * Bw[N][K]^T, 128x128 tile, BK=64,
// 4 waves (each 64x64), global_load_lds + XOR swizzle.
// EPI: 0=qkv(bias+qscale,bf16) 1=proj(bias+res,f32) 2=fc1(bias+gelu,bf16)
//      3=fc2(bias+res,f32)
// ---------------------------------------------------------------------------
template <int EPI>
__global__ __launch_bounds__(256) void gemm_kernel(
    const ushort_t* __restrict__ A, const ushort_t* __restrict__ Bw,
    const float* __restrict__ bias, const float* __restrict__ res,
    void* __restrict__ outp, int M, int N, int K) {
  __shared__ unsigned char lds[32768];
  unsigned char* ldsA = lds;
  unsigned char* ldsB = lds + 16384;
  const int tid = threadIdx.x;
  const int lane = tid & 63, wid = tid >> 6;
  const int ntn = N >> 7;
  const int tileM = (int)(blockIdx.x / ntn) << 7;
  const int tileN = (int)(blockIdx.x % ntn) << 7;
  const unsigned baseoff = ((unsigned)wid << 10) | ((unsigned)lane << 4);

  f32x4 acc[4][4];
#pragma unroll
  for (int i = 0; i < 4; i++)
#pragma unroll
    for (int j = 0; j < 4; j++) acc[i][j] = (f32x4){0.f, 0.f, 0.f, 0.f};

  const int wm = (wid >> 1) << 6;
  const int wn = (wid & 1) << 6;

  for (int k0 = 0; k0 < K; k0 += 64) {
#pragma unroll
    for (int i = 0; i < 4; i++) {
      const unsigned o = baseoff + (unsigned)i * 4096u;
      const unsigned row = o >> 7, cb = o & 127u;
      const unsigned scb = cb ^ ((row & 7u) << 4);
      gload16(A + (size_t)(tileM + row) * K + k0 + (scb >> 1),
              ldsA + (i << 12) + (wid << 10));
      gload16(Bw + (size_t)(tileN + row) * K + k0 + (scb >> 1),
              ldsB + (i << 12) + (wid << 10));
    }
    asm volatile("s_waitcnt vmcnt(0)" ::: "memory");
    __syncthreads();
#pragma unroll
    for (int ks = 0; ks < 2; ks++) {
      bf16x8 af[4], bf[4];
#pragma unroll
      for (int mi = 0; mi < 4; mi++) {
        const int row = wm + mi * 16 + (lane & 15);
        const unsigned cb = ((unsigned)(ks * 64) + (((unsigned)lane >> 4) << 4)) ^ ((row & 7) << 4);
        af[mi] = *(const bf16x8*)(ldsA + row * 128 + cb);
      }
#pragma unroll
      for (int ni = 0; ni < 4; ni++) {
        const int row = wn + ni * 16 + (lane & 15);
        const unsigned cb = ((unsigned)(ks * 64) + (((unsigned)lane >> 4) << 4)) ^ ((row & 7) << 4);
        bf[ni] = *(const bf16x8*)(ldsB + row * 128 + cb);
      }
#pragma unroll
      for (int mi = 0; mi < 4; mi++)
#pragma unroll
        for (int ni = 0; ni < 4; ni++)
          acc[mi][ni] = MFMA16(af[mi], bf[ni], acc[mi][ni]);
    }
    __syncthreads();
  }

  const int cr = ((lane >> 4) << 2);
  const int cc = lane & 15;
#pragma unroll
  for (int mi = 0; mi < 4; mi++) {
#pragma unroll
    for (int ni = 0; ni < 4; ni++) {
      const int colg = tileN + wn + ni * 16 + cc;
      const float bv = bias[colg];
#pragma unroll
      for (int r = 0; r < 4; r++) {
        const int rowg = tileM + wm + mi * 16 + cr + r;
        const size_t oidx = (size_t)rowg * N + colg;
        float v = acc[mi][ni][r] + bv;
        if (EPI == 0) {
          if (colg < 256) v *= 0.17677669529663687f;
          ((ushort_t*)outp)[oidx] = f2bf(v);
        } else if (EPI == 1) {
          ((float*)outp)[oidx] = v + res[oidx];
        } else if (EPI == 2) {
          const float ge = 0.5f * v * (1.0f + erff(v * 0.7071067811865475f));
          ((ushort_t*)outp)[oidx] = f2bf(ge);
        } else {
          ((float*)outp)[oidx] = v + res[oidx];
        }
      }
    }
  }
}

// ---------------------------------------------------------------------------
// Window attention v2: one block per (b_, w, h). 4 waves; wave owns row
// blocks fr = wid, wid+4, wid+8. S in registers, wave-parallel softmax,
// bias via separable index into 13KB LDS table slice.
// ---------------------------------------------------------------------------
__device__ __forceinline__ int Lidx3(int n, int pi, int li, int ln) {
  const int wp = n / 72, rem = n - wp * 72;
  const int wl = rem / 12, ww = rem - wl * 12;
  return ((pi * 2 + wp) * 60 + li * 6 + wl) * 120 + ln * 12 + ww;
}

__global__ __launch_bounds__(256) void attn_kernel(
    const ushort_t* __restrict__ qkv,      // [B*L][768] bf16 (q pre-scaled)
    const float* __restrict__ tblT,        // [320][3312] fp32
    ushort_t* __restrict__ outp) {         // [B*L][256] bf16
  __shared__ float    tslice[3312];
  __shared__ ushort_t Vt[32 * 168];        // V^T, key-dim padded to 160 (zeros)
  __shared__ ushort_t Pw[4][16 * 168];     // per-wave P tile (A-layout)

  const int bi = blockIdx.x;
  const int h  = bi & 7;
  const int w  = (bi >> 3) % 40;
  const int b_ = bi / 320;
  const int b  = b_ / 10, ln = b_ % 10;
  const int pi = w / 10,  li = w % 10;
  const int tid = threadIdx.x, lane = tid & 63, wid = tid >> 6;
  const int lr = lane & 15, hi = lane >> 4;
  const size_t tokbase = (size_t)b * 57600;

  // stage bias table slice (contiguous, coalesced)
  const float* tsl = tblT + (size_t)(w * 8 + h) * 3312;
  for (int i = tid; i < 3312; i += 256) tslice[i] = tsl[i];

  // stage V^T (zero pad keys 144..159)
  for (int idx = tid; idx < 160 * 32; idx += 256) {
    const int n = idx >> 5, e = idx & 31;
    ushort_t val = 0;
    if (n < 144) {
      const size_t rb = (tokbase + Lidx3(n, pi, li, ln)) * 768 + 512 + h * 32 + e;
      val = qkv[rb];
    }
    Vt[e * 168 + n] = val;
  }
  __syncthreads();

  for (int fr = wid; fr < 9; fr += 4) {
    // Q fragment direct from global: rows fr*16+lr, k = hi*8..hi*8+7
    const int qn = fr * 16 + lr;
    const bf16x8 qf = *(const bf16x8*)(
        qkv + (tokbase + Lidx3(qn, pi, li, ln)) * 768 + h * 32 + hi * 8);

    // QK^T: 9 fragments into registers
    f32x4 s[9];
#pragma unroll
    for (int fc = 0; fc < 9; fc++) {
      const int kn = fc * 16 + lr;
      const bf16x8 kf = *(const bf16x8*)(
          qkv + (tokbase + Lidx3(kn, pi, li, ln)) * 768 + 256 + h * 32 + hi * 8);
      f32x4 z = (f32x4){0.f, 0.f, 0.f, 0.f};
      s[fc] = MFMA16(qf, kf, z);
    }

    // + earth position bias: idx = a(n) + b(m) + 11
    int aoff[4];
#pragma unroll
    for (int r = 0; r < 4; r++) {
      const int n = fr * 16 + hi * 4 + r;
      const int zq = n / 72, hq = (n / 12) % 6, wq = n % 12;
      aoff[r] = zq * 828 + hq * 23 + wq + 11;
    }
#pragma unroll
    for (int fc = 0; fc < 9; fc++) {
      const int m = fc * 16 + lr;
      const int zk = m / 72, hk = (m / 12) % 6, wk = m % 12;
      const int boff = zk * 1656 + hk * 138 - wk;
#pragma unroll
      for (int r = 0; r < 4; r++)
        s[fc][r] += tslice[aoff[r] + boff];
    }

    // wave-parallel softmax: reduce over 9 regs + 16-lane group shuffles
    float mx[4], sm[4];
#pragma unroll
    for (int r = 0; r < 4; r++) mx[r] = -1e30f;
#pragma unroll
    for (int fc = 0; fc < 9; fc++)
#pragma unroll
      for (int r = 0; r < 4; r++) mx[r] = fmaxf(mx[r], s[fc][r]);
#pragma unroll
    for (int off = 1; off < 16; off <<= 1)
#pragma unroll
      for (int r = 0; r < 4; r++) mx[r] = fmaxf(mx[r], __shfl_xor(mx[r], off));
#pragma unroll
    for (int r = 0; r < 4; r++) sm[r] = 0.f;
#pragma unroll
    for (int fc = 0; fc < 9; fc++)
#pragma unroll
      for (int r = 0; r < 4; r++) {
        s[fc][r] = __expf(s[fc][r] - mx[r]);
        sm[r] += s[fc][r];
      }
#pragma unroll
    for (int off = 1; off < 16; off <<= 1)
#pragma unroll
      for (int r = 0; r < 4; r++) sm[r] += __shfl_xor(sm[r], off);
    float inv[4];
#pragma unroll
    for (int r = 0; r < 4; r++) inv[r] = 1.0f / sm[r];

    // write P into per-wave A-layout LDS tile (rows hi*4+r, cols m)
    ushort_t* pw = Pw[wid];
#pragma unroll
    for (int fc = 0; fc < 9; fc++)
#pragma unroll
      for (int r = 0; r < 4; r++)
        pw[(hi * 4 + r) * 168 + fc * 16 + lr] = f2bf(s[fc][r] * inv[r]);
#pragma unroll
    for (int r = 0; r < 4; r++)          // zero pad cols 144..159
      pw[(hi * 4 + r) * 168 + 144 + lr] = 0;

    // PV: O[16][32] = P[16][160] * V[160][32]
#pragma unroll
    for (int fcv = 0; fcv < 2; fcv++) {
      f32x4 acc = (f32x4){0.f, 0.f, 0.f, 0.f};
#pragma unroll
      for (int kb = 0; kb < 5; kb++) {
        const bf16x8 a  = *(const bf16x8*)(pw + lr * 168 + kb * 32 + hi * 8);
        const bf16x8 bb = *(const bf16x8*)(Vt + (fcv * 16 + lr) * 168 + kb * 32 + hi * 8);
        acc = MFMA16(a, bb, acc);
      }
      const int e = fcv * 16 + lr;
#pragma unroll
      for (int r = 0; r < 4; r++) {
        const int n = fr * 16 + hi * 4 + r;
        const size_t ob = (tokbase + Lidx3(n, pi, li, ln)) * 256 + h * 32 + e;
        outp[ob] = f2bf(acc[r]);
      }
    }
  }
}

// ---------------------------------------------------------------------------
// launch
// ---------------------------------------------------------------------------
extern "C" void kernel_launch(void* const* d_in, const int* in_sizes, int n_in,
                              void* d_out, int out_size, void* d_ws, size_t ws_size,
                              hipStream_t stream) {
  const float* x      = (const float*)d_in[0];
  const float* n1g    = (const float*)d_in[1];
  const float* n1b    = (const float*)d_in[2];
  const float* qkv_w  = (const float*)d_in[3];
  const float* qkv_b  = (const float*)d_in[4];
  const float* btab   = (const float*)d_in[5];
  const float* proj_w = (const float*)d_in[6];
  const float* proj_b = (const float*)d_in[7];
  const float* n2g    = (const float*)d_in[8];
  const float* n2b    = (const float*)d_in[9];
  const float* fc1_w  = (const float*)d_in[10];
  const float* fc1_b  = (const float*)d_in[11];
  const float* fc2_w  = (const float*)d_in[12];
  const float* fc2_b  = (const float*)d_in[13];
  float* outp = (float*)d_out;

  char* ws = (char*)d_ws;
  // layout:
  //  [0, 176.9M)       qkv bf16 [115200][768]   (later: ln2 out in first 59M)
  //  [176.9M, 235.9M)  ln1 out bf16 (later: attn out bf16)
  //  [235.9M, 240.2M)  tblT fp32 [320][3312]
  //  [59.0M, 294.9M)   fc1 out bf16 (after attention done)
  //  [294.9M, 296.5M)  bf16 weights
  ushort_t* qkvbuf = (ushort_t*)(ws);
  ushort_t* hbuf   = (ushort_t*)(ws + 176947200);
  float*    tblT   = (float*)(ws + 235929600);
  ushort_t* ln2buf = (ushort_t*)(ws);
  ushort_t* fc1buf = (ushort_t*)(ws + 58982400);
  ushort_t* wbuf   = (ushort_t*)(ws + 294912000);
  ushort_t* qkvW = wbuf;
  ushort_t* projW = wbuf + 196608;
  ushort_t* fc1W  = wbuf + 262144;
  ushort_t* fc2W  = wbuf + 524288;

  cvt_kernel<<<768,  256, 0, stream>>>(qkv_w,  qkvW, 196608);
  cvt_kernel<<<256,  256, 0, stream>>>(proj_w, projW, 65536);
  cvt_kernel<<<1024, 256, 0, stream>>>(fc1_w,  fc1W, 262144);
  cvt_kernel<<<1024, 256, 0, stream>>>(fc2_w,  fc2W, 262144);

  ln_kernel<<<28800, 256, 0, stream>>>(x, n1g, n1b, hbuf);
  tbl_transpose<<<4140, 256, 0, stream>>>(btab, tblT);

  gemm_kernel<0><<<900 * 6, 256, 0, stream>>>(hbuf, qkvW, qkv_b, nullptr, qkvbuf, 115200, 768, 256);
  attn_kernel<<<6400, 256, 0, stream>>>(qkvbuf, tblT, hbuf);
  gemm_kernel<1><<<900 * 2, 256, 0, stream>>>(hbuf, projW, proj_b, x, outp, 115200, 256, 256);
  ln_kernel<<<28800, 256, 0, stream>>>(outp, n2g, n2b, ln2buf);
  gemm_kernel<2><<<900 * 8, 256, 0, stream>>>(ln2buf, fc1W, fc1_b, nullptr, fc1buf, 115200, 1024, 256);
  gemm_kernel<3><<<900 * 2, 256, 0, stream>>>(fc1buf, fc2W, fc2_b, outp, outp, 115200, 256, 1024);
}